// Round 8
// baseline (50.877 us; speedup 1.0000x reference)
//
#include <hip/hip_runtime.h>
#include <math.h>

#define REFRACTORY 0.33f
#define FILT_WORDS 8192      // 32 KB LDS coarse filter: 262144 bits
#define QCAP 768             // per-block LDS queue entries (6 KB as int2)

// ws layout:
//   [0,4)    flag (rec_mask byte-mode)
//   [256, 256+128K)   bm (exact 1-bit-per-neuron bitmap, L2-resident)
//   [256+128K, +4*N)  acc
#define WS_BM_OFF  256
#define WS_ACC_OFF (256 + 131072)

// ---------------------------------------------------------------------------
// Kernel 1 (setup): zero exact bitmap; block 0 also detects rec_mask storage
// mode (int32: dwords 0/1; packed bool bytes: dword view gives values > 1).
// ---------------------------------------------------------------------------
__global__ void setup(const unsigned int* __restrict__ rm, int nwords,
                      int* __restrict__ flag,
                      unsigned int* __restrict__ bm, int bmWords) {
    int gid = blockIdx.x * blockDim.x + threadIdx.x;
    int stride = gridDim.x * blockDim.x;
    for (int i = gid; i < bmWords; i += stride) bm[i] = 0u;
    if (blockIdx.x == 0) {
        __shared__ int s;
        if (threadIdx.x == 0) s = 0;
        __syncthreads();
        int found = 0;
        for (int i = threadIdx.x; i < nwords; i += blockDim.x)
            if (rm[i] > 1u) found = 1;
        if (found) atomicOr(&s, 1);
        __syncthreads();
        if (threadIdx.x == 0) *flag = s;
    }
}

// ---------------------------------------------------------------------------
// Kernel 2: mark output neurons in exact bitmap + init their accumulators
// (the only acc slots ever read).
// ---------------------------------------------------------------------------
__global__ void mark_init(const int* __restrict__ out_ids,
                          const float* __restrict__ state,
                          const float* __restrict__ biases,
                          unsigned int* __restrict__ bm,
                          float* __restrict__ acc, int nout) {
    int i = blockIdx.x * blockDim.x + threadIdx.x;
    if (i >= nout) return;
    int n = out_ids[i];
    atomicOr(&bm[((unsigned)n) >> 5], 1u << (n & 31));
    acc[n] = REFRACTORY * state[n] + biases[n];
}

// ---------------------------------------------------------------------------
// Full edge processing. Adds always land on the edge's TRUE dst, so a rare
// unfiltered add is harmless (acc only read at out_ids positions).
// ---------------------------------------------------------------------------
__device__ __forceinline__ void process_edge(
    int d, int e,
    const float* __restrict__ w, const int* __restrict__ src,
    const unsigned char* __restrict__ rmb, const int* __restrict__ input_idx,
    const float* __restrict__ state, const float* __restrict__ inp,
    float* __restrict__ acc, int bytemode) {
    int m = bytemode ? (int)rmb[e] : ((const int*)rmb)[e];
    float v = m ? REFRACTORY * state[src[e]] : inp[input_idx[e]];
    unsafeAtomicAdd(&acc[d], w[e] * v);
}

// ---------------------------------------------------------------------------
// Kernel 3 (fused): build 32 KB coarse LDS filter from out_ids, stream dst,
// enqueue candidates into LDS queue, then drain in-block: exact global-bm
// probe (L2-hot) -> heavy chain for true hits only. 4 blocks/CU.
// ---------------------------------------------------------------------------
__global__ void __launch_bounds__(256, 4)
edge_fused(const int* __restrict__ dst,
           const int* __restrict__ out_ids, int nout,
           int E, int shift,
           const unsigned int* __restrict__ bm,
           const float* __restrict__ w, const int* __restrict__ src,
           const unsigned char* __restrict__ rmb,
           const int* __restrict__ input_idx,
           const float* __restrict__ state, const float* __restrict__ inp,
           float* __restrict__ acc,
           const int* __restrict__ flag) {
    __shared__ unsigned int filt[FILT_WORDS];
    __shared__ int2 lq[QCAP];
    __shared__ int lcnt;

    // zero + build coarse filter from out_ids (L2-hot broadcast read)
    {
        uint4* f4 = (uint4*)filt;
        uint4 z = make_uint4(0, 0, 0, 0);
        for (int i = threadIdx.x; i < FILT_WORDS / 4; i += blockDim.x)
            f4[i] = z;
    }
    if (threadIdx.x == 0) lcnt = 0;
    __syncthreads();
    for (int i = threadIdx.x; i < nout; i += blockDim.x) {
        unsigned g = ((unsigned)out_ids[i]) >> shift;
        atomicOr(&filt[g >> 5], 1u << (g & 31));
    }
    __syncthreads();

    const int bytemode = *flag;
    const int sh5 = shift + 5;
    int gtid = blockIdx.x * blockDim.x + threadIdx.x;
    int gstride = gridDim.x * blockDim.x;
    int nq = E >> 2;
    const int4* d4p = (const int4*)dst;

#define SLOT(dv, ev, valid)                                                    \
    {                                                                          \
        unsigned dd = (unsigned)(dv);                                          \
        bool c = (valid) && ((filt[dd >> sh5] >> ((dd >> shift) & 31)) & 1u);  \
        if (c) {                                                               \
            int off = atomicAdd(&lcnt, 1);                                     \
            if (off < QCAP) lq[off] = make_int2((ev), (int)dd);                \
            else if ((bm[dd >> 5] >> (dd & 31)) & 1u)                          \
                process_edge((int)dd, (ev), w, src, rmb, input_idx,            \
                             state, inp, acc, bytemode);                       \
        }                                                                      \
    }

    for (int t = gtid; t < nq; t += 2 * gstride) {
        int4 A = d4p[t];
        int t2 = t + gstride;
        bool has2 = (t2 < nq);
        int4 B = has2 ? d4p[t2] : make_int4(0, 0, 0, 0);
        int ea = t << 2;
        SLOT(A.x, ea + 0, true);
        SLOT(A.y, ea + 1, true);
        SLOT(A.z, ea + 2, true);
        SLOT(A.w, ea + 3, true);
        int eb = t2 << 2;
        SLOT(B.x, eb + 0, has2);
        SLOT(B.y, eb + 1, has2);
        SLOT(B.z, eb + 2, has2);
        SLOT(B.w, eb + 3, has2);
    }
#undef SLOT

    // tail edges (E not divisible by 4): process inline (true-dst adds)
    int rem = E - nq * 4;
    if (gtid < rem) {
        int e = nq * 4 + gtid;
        int d = dst[e];
        process_edge(d, e, w, src, rmb, input_idx, state, inp, acc, bytemode);
    }

    // drain: exact bm probe first (L2-resident), heavy chain for true hits
    __syncthreads();
    int n = lcnt < QCAP ? lcnt : QCAP;
    for (int i = threadIdx.x; i < n; i += blockDim.x) {
        int2 c = lq[i];
        unsigned d = (unsigned)c.y;
        if ((bm[d >> 5] >> (d & 31)) & 1u)
            process_edge(c.y, c.x, w, src, rmb, input_idx, state, inp, acc, bytemode);
    }
}

// ---------------------------------------------------------------------------
// Kernel 4: activation + gather of the NOUT requested neurons.
// ---------------------------------------------------------------------------
__global__ void gather_out(const float* __restrict__ acc,
                           const int* __restrict__ act_id,
                           const int* __restrict__ out_ids,
                           float* __restrict__ out, int nout) {
    int i = blockIdx.x * blockDim.x + threadIdx.x;
    if (i >= nout) return;
    int n = out_ids[i];
    float x = acc[n];
    float y;
    switch (act_id[n]) {
        case 0: y = x; break;                                   // identity
        case 1: y = fmaxf(x, 0.0f); break;                      // relu
        case 2: y = x > 0.0f ? x : 0.01f * x; break;            // leaky_relu
        case 3: y = fminf(fmaxf(x, 0.0f), 1.0f); break;         // clipped_relu
        case 4: y = tanhf(x); break;                            // tanh
        case 5: y = 1.0f / (1.0f + expf(-x)); break;            // sigmoid
        case 6: y = fmaxf(x, 0.0f) + log1pf(expf(-fabsf(x))); break; // softplus
        default: y = fabsf(x); break;                           // abs
    }
    out[i] = y;
}

extern "C" void kernel_launch(void* const* d_in, const int* in_sizes, int n_in,
                              void* d_out, int out_size, void* d_ws, size_t ws_size,
                              hipStream_t stream) {
    const float* state     = (const float*)d_in[0];
    const float* weights   = (const float*)d_in[1];
    const float* biases    = (const float*)d_in[2];
    const float* inp       = (const float*)d_in[3];
    const int*   src       = (const int*)d_in[4];
    const int*   dst       = (const int*)d_in[5];
    const void*  rec_mask  = d_in[6];
    const int*   input_idx = (const int*)d_in[7];
    const int*   act_id    = (const int*)d_in[8];
    const int*   out_ids   = (const int*)d_in[9];
    float*       out       = (float*)d_out;

    const int N = in_sizes[0];
    const int E = in_sizes[1];
    const int NOUT = out_size;

    int*          flag = (int*)d_ws;
    unsigned int* bm   = (unsigned int*)((char*)d_ws + WS_BM_OFF);
    float*        acc  = (float*)((char*)d_ws + WS_ACC_OFF);

    const int bmWords = (N + 31) / 32;

    // coarse shift: ceil(N >> shift) must fit FILT_WORDS*32 bits
    int shift = 0;
    while ((((long long)N + ((1LL << shift) - 1)) >> shift) > (long long)FILT_WORDS * 32)
        shift++;

    // 1) setup: zero bm, detect rec_mask mode
    int nwords = E / 4;
    if (nwords > 2048) nwords = 2048;
    if (nwords < 1) nwords = 1;
    setup<<<64, 256, 0, stream>>>((const unsigned int*)rec_mask, nwords,
                                  flag, bm, bmWords);

    // 2) mark output neurons in bm + init their accumulators
    mark_init<<<(NOUT + 255) / 256, 256, 0, stream>>>(out_ids, state, biases,
                                                      bm, acc, NOUT);

    // 3) fused: stream dst -> LDS queue -> in-block drain with bm probe
    edge_fused<<<1024, 256, 0, stream>>>(
        dst, out_ids, NOUT, E, shift, bm,
        weights, src, (const unsigned char*)rec_mask, input_idx,
        state, inp, acc, flag);

    // 4) activation + gather
    gather_out<<<(NOUT + 255) / 256, 256, 0, stream>>>(acc, act_id, out_ids, out, NOUT);
}

// Round 9
// 47.510 us; speedup vs baseline: 1.0709x; 1.0709x over previous
//
#include <hip/hip_runtime.h>
#include <math.h>

#define REFRACTORY 0.33f
#define FILT_WORDS 32768     // 128 KB LDS bitmap: 1,048,576 bits (exact, N<=2^20)
#define QCAP 2048            // per-block LDS queue entries (16 KB as int2)

// ws layout:
//   [0,4)            flag (rec_mask byte-mode)
//   [256, 256+128K)  bm (exact global bitmap, built once, copied to LDS)
//   [256+128K, +4*N) acc
#define WS_BM_OFF  256
#define WS_ACC_OFF (256 + 131072)

// ---------------------------------------------------------------------------
// Kernel 1 (mark): block 0 detects rec_mask storage mode (int32: dwords 0/1;
// packed bool bytes: dword view > 1). Blocks 1..: mark out_ids in global bm
// (pre-zeroed by hipMemsetAsync) + init acc = 0.33*state + bias at out
// positions (the only acc slots ever read).
// ---------------------------------------------------------------------------
__global__ void mark_init(const unsigned int* __restrict__ rm, int nwords,
                          int* __restrict__ flag,
                          const int* __restrict__ out_ids,
                          const float* __restrict__ state,
                          const float* __restrict__ biases,
                          unsigned int* __restrict__ bm,
                          float* __restrict__ acc, int nout) {
    if (blockIdx.x == 0) {
        __shared__ int s;
        if (threadIdx.x == 0) s = 0;
        __syncthreads();
        int found = 0;
        for (int i = threadIdx.x; i < nwords; i += blockDim.x)
            if (rm[i] > 1u) found = 1;
        if (found) atomicOr(&s, 1);
        __syncthreads();
        if (threadIdx.x == 0) *flag = s;
    } else {
        int i = (blockIdx.x - 1) * blockDim.x + threadIdx.x;
        if (i < nout) {
            int n = out_ids[i];
            atomicOr(&bm[((unsigned)n) >> 5], 1u << (n & 31));
            acc[n] = REFRACTORY * state[n] + biases[n];
        }
    }
}

// ---------------------------------------------------------------------------
// Full edge processing. Adds always land on the edge's TRUE dst; acc is only
// read at out_ids positions, so any extra add is invisible.
// ---------------------------------------------------------------------------
__device__ __forceinline__ void process_edge(
    int d, int e,
    const float* __restrict__ w, const int* __restrict__ src,
    const unsigned char* __restrict__ rmb, const int* __restrict__ input_idx,
    const float* __restrict__ state, const float* __restrict__ inp,
    float* __restrict__ acc, int bytemode) {
    int m = bytemode ? (int)rmb[e] : ((const int*)rmb)[e];
    float v = m ? REFRACTORY * state[src[e]] : inp[input_idx[e]];
    unsafeAtomicAdd(&acc[d], w[e] * v);
}

// ---------------------------------------------------------------------------
// Kernel 2 (fused): copy prebuilt exact bitmap global->LDS (coalesced uint4,
// L2/L3-hot), stream dst with 4x int4 unroll (16 edges/thread/iter, 4 loads
// in flight), enqueue exact hits into LDS queue, drain at block end with
// lane-independent chains. One block per CU.
// ---------------------------------------------------------------------------
__global__ void __launch_bounds__(1024, 1)
edge_fused(const int* __restrict__ dst,
           const unsigned int* __restrict__ bm,
           int E,
           const float* __restrict__ w, const int* __restrict__ src,
           const unsigned char* __restrict__ rmb,
           const int* __restrict__ input_idx,
           const float* __restrict__ state, const float* __restrict__ inp,
           float* __restrict__ acc,
           const int* __restrict__ flag) {
    __shared__ unsigned int filt[FILT_WORDS];
    __shared__ int2 lq[QCAP];
    __shared__ int lcnt;

    // copy exact bitmap into LDS: 8192 uint4s, coalesced, L2/L3-hot
    {
        const uint4* g4 = (const uint4*)bm;
        uint4* f4 = (uint4*)filt;
        for (int i = threadIdx.x; i < FILT_WORDS / 4; i += blockDim.x)
            f4[i] = g4[i];
    }
    if (threadIdx.x == 0) lcnt = 0;
    __syncthreads();

    const int bytemode = *flag;
    int gtid = blockIdx.x * blockDim.x + threadIdx.x;
    int gstride = gridDim.x * blockDim.x;
    int nq = E >> 2;
    const int4* d4p = (const int4*)dst;

#define SLOT(dv, ev, valid)                                                    \
    {                                                                          \
        unsigned dd = (unsigned)(dv);                                          \
        bool c = (valid) && ((filt[dd >> 5] >> (dd & 31)) & 1u);               \
        if (c) {                                                               \
            int off = atomicAdd(&lcnt, 1);                                     \
            if (off < QCAP) lq[off] = make_int2((ev), (int)dd);                \
            else process_edge((int)dd, (ev), w, src, rmb, input_idx,           \
                              state, inp, acc, bytemode);                      \
        }                                                                      \
    }

    for (int t = gtid; t < nq; t += 4 * gstride) {
        int tB = t + gstride, tC = t + 2 * gstride, tD = t + 3 * gstride;
        bool hB = tB < nq, hC = tC < nq, hD = tD < nq;
        int4 A = d4p[t];
        int4 B = hB ? d4p[tB] : make_int4(0, 0, 0, 0);
        int4 C = hC ? d4p[tC] : make_int4(0, 0, 0, 0);
        int4 D = hD ? d4p[tD] : make_int4(0, 0, 0, 0);
        int ea = t << 2;
        SLOT(A.x, ea + 0, true);
        SLOT(A.y, ea + 1, true);
        SLOT(A.z, ea + 2, true);
        SLOT(A.w, ea + 3, true);
        int eb = tB << 2;
        SLOT(B.x, eb + 0, hB);
        SLOT(B.y, eb + 1, hB);
        SLOT(B.z, eb + 2, hB);
        SLOT(B.w, eb + 3, hB);
        int ec = tC << 2;
        SLOT(C.x, ec + 0, hC);
        SLOT(C.y, ec + 1, hC);
        SLOT(C.z, ec + 2, hC);
        SLOT(C.w, ec + 3, hC);
        int ed = tD << 2;
        SLOT(D.x, ed + 0, hD);
        SLOT(D.y, ed + 1, hD);
        SLOT(D.z, ed + 2, hD);
        SLOT(D.w, ed + 3, hD);
    }
#undef SLOT

    // tail edges (E not divisible by 4): process inline (true-dst adds)
    int rem = E - nq * 4;
    if (gtid < rem) {
        int e = nq * 4 + gtid;
        int d = dst[e];
        process_edge(d, e, w, src, rmb, input_idx, state, inp, acc, bytemode);
    }

    // drain: exact hits only (no false positives), lane-independent chains
    __syncthreads();
    int n = lcnt < QCAP ? lcnt : QCAP;
    for (int i = threadIdx.x; i < n; i += blockDim.x) {
        int2 c = lq[i];
        process_edge(c.y, c.x, w, src, rmb, input_idx, state, inp, acc, bytemode);
    }
}

// ---------------------------------------------------------------------------
// Kernel 3: activation + gather of the NOUT requested neurons.
// ---------------------------------------------------------------------------
__global__ void gather_out(const float* __restrict__ acc,
                           const int* __restrict__ act_id,
                           const int* __restrict__ out_ids,
                           float* __restrict__ out, int nout) {
    int i = blockIdx.x * blockDim.x + threadIdx.x;
    if (i >= nout) return;
    int n = out_ids[i];
    float x = acc[n];
    float y;
    switch (act_id[n]) {
        case 0: y = x; break;                                   // identity
        case 1: y = fmaxf(x, 0.0f); break;                      // relu
        case 2: y = x > 0.0f ? x : 0.01f * x; break;            // leaky_relu
        case 3: y = fminf(fmaxf(x, 0.0f), 1.0f); break;         // clipped_relu
        case 4: y = tanhf(x); break;                            // tanh
        case 5: y = 1.0f / (1.0f + expf(-x)); break;            // sigmoid
        case 6: y = fmaxf(x, 0.0f) + log1pf(expf(-fabsf(x))); break; // softplus
        default: y = fabsf(x); break;                           // abs
    }
    out[i] = y;
}

extern "C" void kernel_launch(void* const* d_in, const int* in_sizes, int n_in,
                              void* d_out, int out_size, void* d_ws, size_t ws_size,
                              hipStream_t stream) {
    const float* state     = (const float*)d_in[0];
    const float* weights   = (const float*)d_in[1];
    const float* biases    = (const float*)d_in[2];
    const float* inp       = (const float*)d_in[3];
    const int*   src       = (const int*)d_in[4];
    const int*   dst       = (const int*)d_in[5];
    const void*  rec_mask  = d_in[6];
    const int*   input_idx = (const int*)d_in[7];
    const int*   act_id    = (const int*)d_in[8];
    const int*   out_ids   = (const int*)d_in[9];
    float*       out       = (float*)d_out;

    const int E = in_sizes[1];
    const int NOUT = out_size;

    int*          flag = (int*)d_ws;
    unsigned int* bm   = (unsigned int*)((char*)d_ws + WS_BM_OFF);
    float*        acc  = (float*)((char*)d_ws + WS_ACC_OFF);

    // 0) zero the global bitmap (graph-safe async memset)
    hipMemsetAsync(bm, 0, FILT_WORDS * 4, stream);

    // 1) mark out_ids in bm + init their accumulators (+ flag detect, blk 0)
    int nwords = E / 4;
    if (nwords > 2048) nwords = 2048;
    if (nwords < 1) nwords = 1;
    int markBlocks = 1 + (NOUT + 255) / 256;
    mark_init<<<markBlocks, 256, 0, stream>>>((const unsigned int*)rec_mask, nwords,
                                              flag, out_ids, state, biases,
                                              bm, acc, NOUT);

    // 2) fused: LDS copy of exact bitmap + dst stream + enqueue + drain
    edge_fused<<<256, 1024, 0, stream>>>(
        dst, bm, E,
        weights, src, (const unsigned char*)rec_mask, input_idx,
        state, inp, acc, flag);

    // 3) activation + gather
    gather_out<<<(NOUT + 255) / 256, 256, 0, stream>>>(acc, act_id, out_ids, out, NOUT);
}

// Round 10
// 46.383 us; speedup vs baseline: 1.0969x; 1.0243x over previous
//
#include <hip/hip_runtime.h>
#include <math.h>

#define REFRACTORY 0.33f
#define FILT_WORDS 32768     // 128 KB LDS bitmap: 1,048,576 bits (exact, N<=2^20)
#define QCAP 2048            // per-block LDS queue entries (16 KB as int2)

// ws layout:
//   [0,4)            flag (rec_mask byte-mode)
//   [256, 256+128K)  bm (exact global bitmap, built once, copied to LDS)
//   [256+128K, +4*N) acc
#define WS_BM_OFF  256
#define WS_ACC_OFF (256 + 131072)

// ---------------------------------------------------------------------------
// Kernel 1 (mark): block 0 detects rec_mask storage mode (int32: dwords 0/1;
// packed bool bytes: dword view > 1). Blocks 1..: mark out_ids in global bm
// (pre-zeroed by hipMemsetAsync) + init acc = 0.33*state + bias at out
// positions (the only acc slots ever read).
// ---------------------------------------------------------------------------
__global__ void mark_init(const unsigned int* __restrict__ rm, int nwords,
                          int* __restrict__ flag,
                          const int* __restrict__ out_ids,
                          const float* __restrict__ state,
                          const float* __restrict__ biases,
                          unsigned int* __restrict__ bm,
                          float* __restrict__ acc, int nout) {
    if (blockIdx.x == 0) {
        __shared__ int s;
        if (threadIdx.x == 0) s = 0;
        __syncthreads();
        int found = 0;
        for (int i = threadIdx.x; i < nwords; i += blockDim.x)
            if (rm[i] > 1u) found = 1;
        if (found) atomicOr(&s, 1);
        __syncthreads();
        if (threadIdx.x == 0) *flag = s;
    } else {
        int i = (blockIdx.x - 1) * blockDim.x + threadIdx.x;
        if (i < nout) {
            int n = out_ids[i];
            atomicOr(&bm[((unsigned)n) >> 5], 1u << (n & 31));
            acc[n] = REFRACTORY * state[n] + biases[n];
        }
    }
}

// ---------------------------------------------------------------------------
// Full edge processing. Adds always land on the edge's TRUE dst; acc is only
// read at out_ids positions, so any extra add is invisible.
// ---------------------------------------------------------------------------
__device__ __forceinline__ void process_edge(
    int d, int e,
    const float* __restrict__ w, const int* __restrict__ src,
    const unsigned char* __restrict__ rmb, const int* __restrict__ input_idx,
    const float* __restrict__ state, const float* __restrict__ inp,
    float* __restrict__ acc, int bytemode) {
    int m = bytemode ? (int)rmb[e] : ((const int*)rmb)[e];
    float v = m ? REFRACTORY * state[src[e]] : inp[input_idx[e]];
    unsafeAtomicAdd(&acc[d], w[e] * v);
}

// ---------------------------------------------------------------------------
// Kernel 2 (fused): copy exact bitmap global->LDS, stream dst 16 edges per
// thread per iteration. Probe phase is BRANCH-FREE (16 independent ds_reads
// pipelined into hit-bit masks); a single rare branch handles enqueue.
// One block per CU.
// ---------------------------------------------------------------------------
__global__ void __launch_bounds__(1024, 1)
edge_fused(const int* __restrict__ dst,
           const unsigned int* __restrict__ bm,
           int E,
           const float* __restrict__ w, const int* __restrict__ src,
           const unsigned char* __restrict__ rmb,
           const int* __restrict__ input_idx,
           const float* __restrict__ state, const float* __restrict__ inp,
           float* __restrict__ acc,
           const int* __restrict__ flag) {
    __shared__ unsigned int filt[FILT_WORDS];
    __shared__ int2 lq[QCAP];
    __shared__ int lcnt;

    // copy exact bitmap into LDS: 8192 uint4s, coalesced, L2/L3-hot
    {
        const uint4* g4 = (const uint4*)bm;
        uint4* f4 = (uint4*)filt;
        for (int i = threadIdx.x; i < FILT_WORDS / 4; i += blockDim.x)
            f4[i] = g4[i];
    }
    if (threadIdx.x == 0) lcnt = 0;
    __syncthreads();

    const int bytemode = *flag;
    int gtid = blockIdx.x * blockDim.x + threadIdx.x;
    int gstride = gridDim.x * blockDim.x;
    int nq = E >> 2;
    const int4* d4p = (const int4*)dst;

// branch-free probe: accumulate hit bit k into mask hv
#define PROBE(dv, hv, k)                                                       \
    { unsigned dd = (unsigned)(dv);                                            \
      hv |= ((filt[dd >> 5] >> (dd & 31)) & 1u) << (k); }

#define ENQ(ev, dv)                                                            \
    { int off = atomicAdd(&lcnt, 1);                                           \
      if (off < QCAP) lq[off] = make_int2((ev), (int)(dv));                    \
      else process_edge((int)(dv), (ev), w, src, rmb, input_idx,               \
                        state, inp, acc, bytemode); }

    for (int t = gtid; t < nq; t += 4 * gstride) {
        int tB = t + gstride, tC = t + 2 * gstride, tD = t + 3 * gstride;
        bool vB = tB < nq, vC = tC < nq, vD = tD < nq;
        int4 A = d4p[t];
        int4 B = vB ? d4p[tB] : make_int4(0, 0, 0, 0);
        int4 C = vC ? d4p[tC] : make_int4(0, 0, 0, 0);
        int4 D = vD ? d4p[tD] : make_int4(0, 0, 0, 0);

        unsigned mA = 0, mB = 0, mC = 0, mD = 0;
        PROBE(A.x, mA, 0) PROBE(A.y, mA, 1) PROBE(A.z, mA, 2) PROBE(A.w, mA, 3)
        PROBE(B.x, mB, 0) PROBE(B.y, mB, 1) PROBE(B.z, mB, 2) PROBE(B.w, mB, 3)
        PROBE(C.x, mC, 0) PROBE(C.y, mC, 1) PROBE(C.z, mC, 2) PROBE(C.w, mC, 3)
        PROBE(D.x, mD, 0) PROBE(D.y, mD, 1) PROBE(D.z, mD, 2) PROBE(D.w, mD, 3)
        if (!vB) mB = 0;
        if (!vC) mC = 0;
        if (!vD) mD = 0;

        if (mA | mB | mC | mD) {   // rare: ~12% of lanes per batch
            int ea = t << 2, eb = tB << 2, ec = tC << 2, ed = tD << 2;
            if (mA & 1) ENQ(ea + 0, A.x)
            if (mA & 2) ENQ(ea + 1, A.y)
            if (mA & 4) ENQ(ea + 2, A.z)
            if (mA & 8) ENQ(ea + 3, A.w)
            if (mB & 1) ENQ(eb + 0, B.x)
            if (mB & 2) ENQ(eb + 1, B.y)
            if (mB & 4) ENQ(eb + 2, B.z)
            if (mB & 8) ENQ(eb + 3, B.w)
            if (mC & 1) ENQ(ec + 0, C.x)
            if (mC & 2) ENQ(ec + 1, C.y)
            if (mC & 4) ENQ(ec + 2, C.z)
            if (mC & 8) ENQ(ec + 3, C.w)
            if (mD & 1) ENQ(ed + 0, D.x)
            if (mD & 2) ENQ(ed + 1, D.y)
            if (mD & 4) ENQ(ed + 2, D.z)
            if (mD & 8) ENQ(ed + 3, D.w)
        }
    }
#undef PROBE
#undef ENQ

    // tail edges (E not divisible by 4): process inline (true-dst adds)
    int rem = E - nq * 4;
    if (gtid < rem) {
        int e = nq * 4 + gtid;
        int d = dst[e];
        process_edge(d, e, w, src, rmb, input_idx, state, inp, acc, bytemode);
    }

    // drain: exact hits only (no false positives), lane-independent chains
    __syncthreads();
    int n = lcnt < QCAP ? lcnt : QCAP;
    for (int i = threadIdx.x; i < n; i += blockDim.x) {
        int2 c = lq[i];
        process_edge(c.y, c.x, w, src, rmb, input_idx, state, inp, acc, bytemode);
    }
}

// ---------------------------------------------------------------------------
// Kernel 3: activation + gather of the NOUT requested neurons.
// ---------------------------------------------------------------------------
__global__ void gather_out(const float* __restrict__ acc,
                           const int* __restrict__ act_id,
                           const int* __restrict__ out_ids,
                           float* __restrict__ out, int nout) {
    int i = blockIdx.x * blockDim.x + threadIdx.x;
    if (i >= nout) return;
    int n = out_ids[i];
    float x = acc[n];
    float y;
    switch (act_id[n]) {
        case 0: y = x; break;                                   // identity
        case 1: y = fmaxf(x, 0.0f); break;                      // relu
        case 2: y = x > 0.0f ? x : 0.01f * x; break;            // leaky_relu
        case 3: y = fminf(fmaxf(x, 0.0f), 1.0f); break;         // clipped_relu
        case 4: y = tanhf(x); break;                            // tanh
        case 5: y = 1.0f / (1.0f + expf(-x)); break;            // sigmoid
        case 6: y = fmaxf(x, 0.0f) + log1pf(expf(-fabsf(x))); break; // softplus
        default: y = fabsf(x); break;                           // abs
    }
    out[i] = y;
}

extern "C" void kernel_launch(void* const* d_in, const int* in_sizes, int n_in,
                              void* d_out, int out_size, void* d_ws, size_t ws_size,
                              hipStream_t stream) {
    const float* state     = (const float*)d_in[0];
    const float* weights   = (const float*)d_in[1];
    const float* biases    = (const float*)d_in[2];
    const float* inp       = (const float*)d_in[3];
    const int*   src       = (const int*)d_in[4];
    const int*   dst       = (const int*)d_in[5];
    const void*  rec_mask  = d_in[6];
    const int*   input_idx = (const int*)d_in[7];
    const int*   act_id    = (const int*)d_in[8];
    const int*   out_ids   = (const int*)d_in[9];
    float*       out       = (float*)d_out;

    const int E = in_sizes[1];
    const int NOUT = out_size;

    int*          flag = (int*)d_ws;
    unsigned int* bm   = (unsigned int*)((char*)d_ws + WS_BM_OFF);
    float*        acc  = (float*)((char*)d_ws + WS_ACC_OFF);

    // 0) zero the global bitmap (graph-safe async memset)
    hipMemsetAsync(bm, 0, FILT_WORDS * 4, stream);

    // 1) mark out_ids in bm + init their accumulators (+ flag detect, blk 0)
    int nwords = E / 4;
    if (nwords > 2048) nwords = 2048;
    if (nwords < 1) nwords = 1;
    int markBlocks = 1 + (NOUT + 255) / 256;
    mark_init<<<markBlocks, 256, 0, stream>>>((const unsigned int*)rec_mask, nwords,
                                              flag, out_ids, state, biases,
                                              bm, acc, NOUT);

    // 2) fused: LDS copy of exact bitmap + branch-free probe stream + drain
    edge_fused<<<256, 1024, 0, stream>>>(
        dst, bm, E,
        weights, src, (const unsigned char*)rec_mask, input_idx,
        state, inp, acc, flag);

    // 3) activation + gather
    gather_out<<<(NOUT + 255) / 256, 256, 0, stream>>>(acc, act_id, out_ids, out, NOUT);
}

// Round 11
// 37.790 us; speedup vs baseline: 1.3463x; 1.2274x over previous
//
#include <hip/hip_runtime.h>
#include <math.h>

#define REFRACTORY 0.33f
#define FILT_WORDS 32768     // 128 KB LDS bitmap: 1,048,576 bits (exact, N<=2^20)
#define QWCAP 128            // per-WAVE queue entries (int2) -> 16 KB total
#define NWAVES 16            // 1024 threads / 64
#define DRAIN_THRESH 16

// ws layout: [0,4) flag (rec_mask byte-mode); [256, 256+4*N) acc
#define WS_ACC_OFF 256

// ---------------------------------------------------------------------------
// Kernel 1 (setup): block 0 detects rec_mask storage mode (int32: dwords 0/1;
// packed bool bytes: dword view > 1); blocks 1.. init acc = 0.33*state + bias
// at output-neuron positions (the only acc slots ever read).
// ---------------------------------------------------------------------------
__global__ void setup(const unsigned int* __restrict__ rm, int nwords,
                      int* __restrict__ flag,
                      const int* __restrict__ out_ids,
                      const float* __restrict__ state,
                      const float* __restrict__ biases,
                      float* __restrict__ acc, int nout) {
    if (blockIdx.x == 0) {
        __shared__ int s;
        if (threadIdx.x == 0) s = 0;
        __syncthreads();
        int found = 0;
        for (int i = threadIdx.x; i < nwords; i += blockDim.x)
            if (rm[i] > 1u) found = 1;
        if (found) atomicOr(&s, 1);
        __syncthreads();
        if (threadIdx.x == 0) *flag = s;
    } else {
        int i = (blockIdx.x - 1) * blockDim.x + threadIdx.x;
        if (i < nout) {
            int n = out_ids[i];
            acc[n] = REFRACTORY * state[n] + biases[n];
        }
    }
}

// ---------------------------------------------------------------------------
// Full edge processing. Adds always land on the edge's TRUE dst; acc is only
// read at out_ids positions, so any extra add (shift>0 FPs) is invisible.
// ---------------------------------------------------------------------------
__device__ __forceinline__ void process_edge(
    int d, int e,
    const float* __restrict__ w, const int* __restrict__ src,
    const unsigned char* __restrict__ rmb, const int* __restrict__ input_idx,
    const float* __restrict__ state, const float* __restrict__ inp,
    float* __restrict__ acc, int bytemode) {
    int m = bytemode ? (int)rmb[e] : ((const int*)rmb)[e];
    float v = m ? REFRACTORY * state[src[e]] : inp[input_idx[e]];
    unsafeAtomicAdd(&acc[d], w[e] * v);
}

// ---------------------------------------------------------------------------
// Kernel 2 (fused): exact 128 KB LDS bitmap built in-block from out_ids.
// Stream dst with branch-free probes into PER-WAVE queues; drain own queue
// whenever it reaches DRAIN_THRESH (staggered across waves -> random drain
// traffic overlaps sequential stream traffic chip-wide). No barriers after
// the filter build. One block per CU.
// ---------------------------------------------------------------------------
__global__ void __launch_bounds__(1024, 1)
edge_fused(const int* __restrict__ dst,
           const int* __restrict__ out_ids, int nout,
           int E, int shift,
           const float* __restrict__ w, const int* __restrict__ src,
           const unsigned char* __restrict__ rmb,
           const int* __restrict__ input_idx,
           const float* __restrict__ state, const float* __restrict__ inp,
           float* __restrict__ acc,
           const int* __restrict__ flag) {
    __shared__ unsigned int filt[FILT_WORDS];
    __shared__ int2 lq[NWAVES * QWCAP];
    __shared__ int wcnt[NWAVES];

    // zero bitmap
    {
        uint4* f4 = (uint4*)filt;
        uint4 z = make_uint4(0, 0, 0, 0);
        for (int i = threadIdx.x; i < FILT_WORDS / 4; i += blockDim.x)
            f4[i] = z;
    }
    if ((threadIdx.x & 63) == 0) wcnt[threadIdx.x >> 6] = 0;
    __syncthreads();
    // build exact membership bitmap from out_ids (L2-hot broadcast read)
    for (int i = threadIdx.x; i < nout; i += blockDim.x) {
        unsigned g = ((unsigned)out_ids[i]) >> shift;
        atomicOr(&filt[g >> 5], 1u << (g & 31));
    }
    __syncthreads();

    const int bytemode = *flag;
    const int lane = threadIdx.x & 63;
    const int wv = threadIdx.x >> 6;
    int2* wq = &lq[wv * QWCAP];
    int* mycnt = &wcnt[wv];

    int gtid = blockIdx.x * blockDim.x + threadIdx.x;
    int gstride = gridDim.x * blockDim.x;
    int nq = E >> 2;
    const int4* d4p = (const int4*)dst;

#define PROBE(dv, hv, k)                                                       \
    { unsigned dd = (unsigned)(dv) >> shift;                                   \
      hv |= ((filt[dd >> 5] >> (dd & 31)) & 1u) << (k); }

#define ENQ(ev, dv)                                                            \
    { int off = atomicAdd(mycnt, 1);                                           \
      if (off < QWCAP) wq[off] = make_int2((ev), (int)(dv));                   \
      else process_edge((int)(dv), (ev), w, src, rmb, input_idx,               \
                        state, inp, acc, bytemode); }

    for (int t = gtid; t < nq; t += 2 * gstride) {
        int tB = t + gstride;
        bool vB = tB < nq;
        int4 A = d4p[t];
        int4 B = vB ? d4p[tB] : make_int4(0, 0, 0, 0);

        unsigned mA = 0, mB = 0;
        PROBE(A.x, mA, 0) PROBE(A.y, mA, 1) PROBE(A.z, mA, 2) PROBE(A.w, mA, 3)
        PROBE(B.x, mB, 0) PROBE(B.y, mB, 1) PROBE(B.z, mB, 2) PROBE(B.w, mB, 3)
        if (!vB) mB = 0;

        if (mA | mB) {
            int ea = t << 2, eb = tB << 2;
            if (mA & 1) ENQ(ea + 0, A.x)
            if (mA & 2) ENQ(ea + 1, A.y)
            if (mA & 4) ENQ(ea + 2, A.z)
            if (mA & 8) ENQ(ea + 3, A.w)
            if (mB & 1) ENQ(eb + 0, B.x)
            if (mB & 2) ENQ(eb + 1, B.y)
            if (mB & 4) ENQ(eb + 2, B.z)
            if (mB & 8) ENQ(eb + 3, B.w)
        }

        // staggered per-wave drain: overlap random hit traffic with the
        // other waves' streaming (no barriers, wave-uniform condition)
        int have = *mycnt;
        if (have >= DRAIN_THRESH) {
            int nn = have < QWCAP ? have : QWCAP;
            for (int i = lane; i < nn; i += 64) {
                int2 c = wq[i];
                process_edge(c.y, c.x, w, src, rmb, input_idx,
                             state, inp, acc, bytemode);
            }
            if (lane == 0) *mycnt = 0;
        }
    }
#undef PROBE
#undef ENQ

    // tail edges (E not divisible by 4): process inline (true-dst adds)
    int rem = E - nq * 4;
    if (gtid < rem) {
        int e = nq * 4 + gtid;
        int d = dst[e];
        process_edge(d, e, w, src, rmb, input_idx, state, inp, acc, bytemode);
    }

    // final per-wave drain
    {
        int have = *mycnt;
        int nn = have < QWCAP ? have : QWCAP;
        for (int i = lane; i < nn; i += 64) {
            int2 c = wq[i];
            process_edge(c.y, c.x, w, src, rmb, input_idx,
                         state, inp, acc, bytemode);
        }
    }
}

// ---------------------------------------------------------------------------
// Kernel 3: activation + gather of the NOUT requested neurons.
// ---------------------------------------------------------------------------
__global__ void gather_out(const float* __restrict__ acc,
                           const int* __restrict__ act_id,
                           const int* __restrict__ out_ids,
                           float* __restrict__ out, int nout) {
    int i = blockIdx.x * blockDim.x + threadIdx.x;
    if (i >= nout) return;
    int n = out_ids[i];
    float x = acc[n];
    float y;
    switch (act_id[n]) {
        case 0: y = x; break;                                   // identity
        case 1: y = fmaxf(x, 0.0f); break;                      // relu
        case 2: y = x > 0.0f ? x : 0.01f * x; break;            // leaky_relu
        case 3: y = fminf(fmaxf(x, 0.0f), 1.0f); break;         // clipped_relu
        case 4: y = tanhf(x); break;                            // tanh
        case 5: y = 1.0f / (1.0f + expf(-x)); break;            // sigmoid
        case 6: y = fmaxf(x, 0.0f) + log1pf(expf(-fabsf(x))); break; // softplus
        default: y = fabsf(x); break;                           // abs
    }
    out[i] = y;
}

extern "C" void kernel_launch(void* const* d_in, const int* in_sizes, int n_in,
                              void* d_out, int out_size, void* d_ws, size_t ws_size,
                              hipStream_t stream) {
    const float* state     = (const float*)d_in[0];
    const float* weights   = (const float*)d_in[1];
    const float* biases    = (const float*)d_in[2];
    const float* inp       = (const float*)d_in[3];
    const int*   src       = (const int*)d_in[4];
    const int*   dst       = (const int*)d_in[5];
    const void*  rec_mask  = d_in[6];
    const int*   input_idx = (const int*)d_in[7];
    const int*   act_id    = (const int*)d_in[8];
    const int*   out_ids   = (const int*)d_in[9];
    float*       out       = (float*)d_out;

    const int N = in_sizes[0];
    const int E = in_sizes[1];
    const int NOUT = out_size;

    int*   flag = (int*)d_ws;
    float* acc  = (float*)((char*)d_ws + WS_ACC_OFF);

    // filter granularity: shift=0 (exact) when N fits 2^20 bits
    int shift = 0;
    while ((((long long)N + ((1LL << shift) - 1)) >> shift) > (long long)FILT_WORDS * 32)
        shift++;

    // 1) setup: detect rec_mask mode + init acc at out positions
    int nwords = E / 4;
    if (nwords > 2048) nwords = 2048;
    if (nwords < 1) nwords = 1;
    int setupBlocks = 1 + (NOUT + 255) / 256;
    setup<<<setupBlocks, 256, 0, stream>>>((const unsigned int*)rec_mask, nwords,
                                           flag, out_ids, state, biases, acc, NOUT);

    // 2) fused: in-block exact filter + stream + per-wave staggered drains
    edge_fused<<<256, 1024, 0, stream>>>(
        dst, out_ids, NOUT, E, shift,
        weights, src, (const unsigned char*)rec_mask, input_idx,
        state, inp, acc, flag);

    // 3) activation + gather
    gather_out<<<(NOUT + 255) / 256, 256, 0, stream>>>(acc, act_id, out_ids, out, NOUT);
}